// Round 12
// baseline (237.075 us; speedup 1.0000x reference)
//
#include <hip/hip_runtime.h>
#include <math.h>

namespace {
constexpr int B = 2;
constexpr int N = 2048;
constexpr int DIM = 512;
constexpr int H = 8;
constexpr int MEM = 16;
constexpr int J = MEM + N;       // 2064
constexpr int CHUNK = 256;
constexpr int CMAX = 9;          // ceil(2064/256)
constexpr float S2 = 0.125f * 1.4426950408889634f;  // SCALE * log2(e)
// e-buffer: per b, sum_t (16t+32) j-rows * 16 i * 8 h1 bf16 elems
constexpr size_t EPB = 17170432;        // 134144 * 128
}

typedef __attribute__((ext_vector_type(8))) short short8;
typedef __attribute__((ext_vector_type(2))) float floatx2;
typedef __attribute__((ext_vector_type(4))) float floatx4;
typedef __attribute__((ext_vector_type(4))) unsigned short ushortx4;
typedef __attribute__((ext_vector_type(8))) unsigned short ushortx8;

__device__ inline unsigned short f2bf(float f) {
    unsigned int u = __float_as_uint(f);
    u += 0x7fffu + ((u >> 16) & 1u);   // RNE
    return (unsigned short)(u >> 16);
}
__device__ inline unsigned int pk2bf(float a, float b) {
    return ((__float_as_uint(a) + 0x8000u) >> 16) |
           ((__float_as_uint(b) + 0x8000u) & 0xffff0000u);
}

// ---------------- P: fused prologue — x conv, W transposes, memkv, zeroing
__global__ __launch_bounds__(256)
void prep(const float* __restrict__ x,
          const float* __restrict__ Wq, const float* __restrict__ Wk,
          const float* __restrict__ Wv, const float* __restrict__ Wo,
          const float* __restrict__ mem_k, const float* __restrict__ mem_v,
          unsigned short* __restrict__ x16,
          unsigned short* __restrict__ tq, unsigned short* __restrict__ tk,
          unsigned short* __restrict__ tv, unsigned short* __restrict__ to_,
          unsigned short* __restrict__ k16, unsigned short* __restrict__ vt16,
          float* __restrict__ zbuf)
{
    __shared__ __align__(16) unsigned short tile[64][72];
    const int bid = blockIdx.x;
    const int t = threadIdx.x;

    if (bid < 1024) {                      // ---- x conversion
        const size_t base = ((size_t)bid * 256 + t) * 8;
        const float4 a = *(const float4*)(x + base);
        const float4 b = *(const float4*)(x + base + 4);
        ushortx8 o = { f2bf(a.x), f2bf(a.y), f2bf(a.z), f2bf(a.w),
                       f2bf(b.x), f2bf(b.y), f2bf(b.z), f2bf(b.w) };
        *(ushortx8*)(x16 + base) = o;
        return;
    }
    if (bid < 1280) {                      // ---- W -> WT bf16 transpose
        const int idx = bid - 1024;
        const int z = idx >> 6, rem = idx & 63;
        const float* __restrict__ W = (z == 0) ? Wq : (z == 1) ? Wk : (z == 2) ? Wv : Wo;
        unsigned short* __restrict__ WT = (z == 0) ? tq : (z == 1) ? tk : (z == 2) ? tv : to_;
        const int k0 = (rem >> 3) * 64, n0 = (rem & 7) * 64;

        const int rrow = t >> 4, rcol = (t & 15) * 4;
#pragma unroll
        for (int rr = 0; rr < 4; ++rr) {
            const int row = rrow + rr * 16;
            const float4 v = *(const float4*)(W + (size_t)(k0 + row) * DIM + n0 + rcol);
            tile[rcol + 0][row] = f2bf(v.x);
            tile[rcol + 1][row] = f2bf(v.y);
            tile[rcol + 2][row] = f2bf(v.z);
            tile[rcol + 3][row] = f2bf(v.w);
        }
        __syncthreads();
        const int orow = t >> 2, oseg = (t & 3) * 16;
        *(ushortx8*)(WT + (size_t)(n0 + orow) * DIM + k0 + oseg) =
            *(const ushortx8*)(&tile[orow][oseg]);
        *(ushortx8*)(WT + (size_t)(n0 + orow) * DIM + k0 + oseg + 8) =
            *(const ushortx8*)(&tile[orow][oseg + 8]);
        return;
    }
    if (bid < 1312) {                      // ---- mem_k/mem_v scatter
        const int idx = (bid - 1280) * 256 + t;  // H*MEM*64 = 8192
        if (idx >= H * MEM * 64) return;
        const int h0 = idx >> 10;
        const int rd = idx & 1023;
        const int r = rd >> 6, d = rd & 63;
        const unsigned short kk = f2bf(mem_k[idx]);
        const unsigned short vv = f2bf(mem_v[idx]);
#pragma unroll
        for (int bb = 0; bb < B; ++bb) {
            k16[((size_t)(bb * H + h0) * J + r) * 64 + d] = kk;
            vt16[((size_t)(bb * H + h0) * 64 + d) * J + r] = vv;
        }
        return;
    }
    {                                      // ---- zero ao + lbuf (8.52 MB)
        const size_t off = ((size_t)(bid - 1312) * 256 + t) * 4;
        *(float4*)(zbuf + off) = make_float4(0.f, 0.f, 0.f, 0.f);
    }
}

// ---------------- K1: QKV projection GEMM — 128x128 m97-style -------------
// global_load_lds staging (16B), dbuf LDS, 4 waves x (64x64), acc[4][4].
// Output layouts: q16[b,h,N,64] / k16[b,h,J,64] / vt16[b,h,64,J]
__global__ __launch_bounds__(256)
void qkv_gemm(const unsigned short* __restrict__ x16, const unsigned short* __restrict__ tq,
              const unsigned short* __restrict__ tk, const unsigned short* __restrict__ tv,
              unsigned short* __restrict__ q16, unsigned short* __restrict__ k16,
              unsigned short* __restrict__ vt16)
{
    const int which = blockIdx.z;
    const unsigned short* __restrict__ WT = (which == 0) ? tq : (which == 1) ? tk : tv;
    const int t = threadIdx.x;
    const int lane = t & 63, w = t >> 6;
    const int iL = lane & 15, quad = lane >> 4;
    const int wr = w >> 1, wc = w & 1;
    const int mb = blockIdx.x * 128;
    const int n0 = blockIdx.y * 128;

    __shared__ __align__(16) unsigned short As[2][128][32];  // 16 KB
    __shared__ __align__(16) unsigned short Bs[2][128][32];  // 16 KB

    const int srow = lane >> 2, scol = (lane & 3) * 8;   // per-lane source coords

    auto STAGE = [&](int buf, int k0) {
#pragma unroll
        for (int cc = 0; cc < 2; ++cc) {
            const int rb = w * 32 + cc * 16;             // wave-uniform row base
            const unsigned short* sa = x16 + (size_t)(mb + rb + srow) * DIM + k0 + scol;
            __builtin_amdgcn_global_load_lds(
                (const __attribute__((address_space(1))) unsigned int*)sa,
                (__attribute__((address_space(3))) unsigned int*)(&As[buf][rb][0]),
                16, 0, 0);
            const unsigned short* sb = WT + (size_t)(n0 + rb + srow) * DIM + k0 + scol;
            __builtin_amdgcn_global_load_lds(
                (const __attribute__((address_space(1))) unsigned int*)sb,
                (__attribute__((address_space(3))) unsigned int*)(&Bs[buf][rb][0]),
                16, 0, 0);
        }
    };

    floatx4 acc[4][4];
#pragma unroll
    for (int mi = 0; mi < 4; ++mi)
#pragma unroll
        for (int ni = 0; ni < 4; ++ni) acc[mi][ni] = (floatx4){0.f, 0.f, 0.f, 0.f};

    STAGE(0, 0);
    __syncthreads();

    for (int it = 0; it < 16; ++it) {
        const int buf = it & 1;
        if (it + 1 < 16) STAGE(buf ^ 1, (it + 1) * 32);
        short8 aF[4], bF[4];
#pragma unroll
        for (int mi = 0; mi < 4; ++mi)
            aF[mi] = *(const short8*)(&As[buf][wr * 64 + mi * 16 + iL][quad * 8]);
#pragma unroll
        for (int ni = 0; ni < 4; ++ni)
            bF[ni] = *(const short8*)(&Bs[buf][wc * 64 + ni * 16 + iL][quad * 8]);
#pragma unroll
        for (int mi = 0; mi < 4; ++mi)
#pragma unroll
            for (int ni = 0; ni < 4; ++ni)
                acc[mi][ni] = __builtin_amdgcn_mfma_f32_16x16x32_bf16(
                    aF[mi], bF[ni], acc[mi][ni], 0, 0, 0);
        __syncthreads();   // staging(buf^1) drained + all reads of buf done
    }

#pragma unroll
    for (int mi = 0; mi < 4; ++mi) {
#pragma unroll
        for (int ni = 0; ni < 4; ++ni) {
#pragma unroll
            for (int r = 0; r < 4; ++r) {
                const int m = mb + wr * 64 + mi * 16 + quad * 4 + r;
                const int n = n0 + wc * 64 + ni * 16 + iL;
                const int h0 = n >> 6, d = n & 63;
                const int bb = m >> 11, ii = m & (N - 1);
                const unsigned short v = f2bf(acc[mi][ni][r]);
                if (which == 0)
                    q16[((size_t)(bb * H + h0) * N + ii) * 64 + d] = v;
                else if (which == 1)
                    k16[((size_t)(bb * H + h0) * J + MEM + ii) * 64 + d] = v;
                else
                    vt16[((size_t)(bb * H + h0) * 64 + d) * J + MEM + ii] = v;
            }
        }
    }
}

// ---------------- K2a: scores pass — r8-exact (measured 64.9 us) ----------
__global__ __launch_bounds__(256)
void attn_scores(const unsigned short* __restrict__ qb, const unsigned short* __restrict__ kb,
                 const float* __restrict__ prep_p, float* __restrict__ lbuf,
                 unsigned short* __restrict__ e16)
{
    const int c = blockIdx.x, tt = 127 - blockIdx.y, b = blockIdx.z;
    const int i0 = tt * 16;
    const int jlim = i0 + 32;            // == min(J, i0+32) for all tt
    const int jstart = c * CHUNK;
    if (jstart >= jlim) return;
    const int jend = min(jstart + CHUNK, jlim);

    __shared__ __align__(16) unsigned short q_s[8][16][64];  // 16 KB
    __shared__ __align__(16) float pre_s[64];
    const int t = threadIdx.x;
    if (t < 64) pre_s[t] = prep_p[t];
#pragma unroll
    for (int u4 = 0; u4 < 4; ++u4) {
        const int u = t + u4 * 256;          // over 1024 groups of 8
        const int h = u >> 7, rem = u & 127, i = rem >> 3, seg = (rem & 7) * 8;
        *(ushortx8*)(&q_s[h][i][seg]) =
            *(const ushortx8*)(qb + ((size_t)(b * H + h) * N + i0 + i) * 64 + seg);
    }
    __syncthreads();

    const int lane = t & 63, w = t >> 6;
    const int iL = lane & 15, quad = lane >> 4;
    const int i = i0 + iL;
    const size_t ebase = (size_t)b * EPB + (size_t)(8 * tt * tt + 24 * tt) * 128;

    float l_acc[8];
#pragma unroll
    for (int h1 = 0; h1 < 8; ++h1) l_acc[h1] = 0.f;

    bool any = false;
    for (int j0 = jstart + w * 16; j0 < jend; j0 += 64) {
        any = true;
        float dots[8][4];
#pragma unroll
        for (int h1 = 0; h1 < 8; ++h1)
#pragma unroll
            for (int r = 0; r < 4; ++r) dots[h1][r] = 0.f;

        // k prefetch chain over h0
        const unsigned short* kp0 = kb + ((size_t)(b * H) * J + j0 + iL) * 64 + quad * 8;
        short8 kc0 = *(const short8*)kp0;
        short8 kc1 = *(const short8*)(kp0 + 32);
#pragma unroll
        for (int h0 = 0; h0 < 8; ++h0) {
            short8 kn0, kn1;
            if (h0 < 7) {
                const unsigned short* kpn =
                    kb + ((size_t)(b * H + h0 + 1) * J + j0 + iL) * 64 + quad * 8;
                kn0 = *(const short8*)kpn;
                kn1 = *(const short8*)(kpn + 32);
            }
            const short8 qf0 = *(const short8*)(&q_s[h0][iL][quad * 8]);
            const short8 qf1 = *(const short8*)(&q_s[h0][iL][quad * 8 + 32]);
            floatx4 a = {0.f, 0.f, 0.f, 0.f};
            a = __builtin_amdgcn_mfma_f32_16x16x32_bf16(kc0, qf0, a, 0, 0, 0);
            a = __builtin_amdgcn_mfma_f32_16x16x32_bf16(kc1, qf1, a, 0, 0, 0);
            const float4 pr0 = *(const float4*)(&pre_s[h0 * 8]);
            const float4 pr1 = *(const float4*)(&pre_s[h0 * 8 + 4]);
#pragma unroll
            for (int r = 0; r < 4; ++r) {
                const float av = a[r];
                dots[0][r] = fmaf(av, pr0.x, dots[0][r]);
                dots[1][r] = fmaf(av, pr0.y, dots[1][r]);
                dots[2][r] = fmaf(av, pr0.z, dots[2][r]);
                dots[3][r] = fmaf(av, pr0.w, dots[3][r]);
                dots[4][r] = fmaf(av, pr1.x, dots[4][r]);
                dots[5][r] = fmaf(av, pr1.y, dots[5][r]);
                dots[6][r] = fmaf(av, pr1.z, dots[6][r]);
                dots[7][r] = fmaf(av, pr1.w, dots[7][r]);
            }
            kc0 = kn0; kc1 = kn1;
        }

        unsigned int epk[4][4];
        float etmp[4];
#pragma unroll
        for (int h1 = 0; h1 < 8; ++h1) {
            const float slopeE = 1.4426950408889634f / (float)(2 << h1);
#pragma unroll
            for (int r = 0; r < 4; ++r) {
                const int j = j0 + quad * 4 + r;
                const bool vis = (j - MEM) <= i;
                const float e = vis ? exp2f(fmaf(dots[h1][r], S2, slopeE * (float)(j - i - MEM)))
                                    : 0.f;
                l_acc[h1] += e;
                if (h1 & 1) epk[r][h1 >> 1] = pk2bf(etmp[r], e);
                else        etmp[r] = e;
            }
        }
#pragma unroll
        for (int r = 0; r < 4; ++r) {
            uint4 o = make_uint4(epk[r][0], epk[r][1], epk[r][2], epk[r][3]);
            *(uint4*)(e16 + ebase + (size_t)((j0 + quad * 4 + r) * 16 + iL) * 8) = o;
        }
    }

#pragma unroll
    for (int h1 = 0; h1 < 8; ++h1) {
        float v = l_acc[h1];
        v += __shfl_xor(v, 16);
        v += __shfl_xor(v, 32);
        if (quad == 0 && any)
            atomicAdd(lbuf + ((size_t)(b * 128 + tt) * 8 + h1) * 16 + iL, v);
    }
}

// ---------------- K2b: pv pass — 3-deep e-prefetch, dbuf LDS, PV-MFMA -----
__global__ __launch_bounds__(256)
void attn_pv2(const unsigned short* __restrict__ e16, const unsigned short* __restrict__ vt,
              const float* __restrict__ postp, const float* __restrict__ hsp,
              const float* __restrict__ lbuf, float* __restrict__ ao)
{
    const int c = blockIdx.x, tt = 127 - blockIdx.y, b = blockIdx.z;
    const int i0 = tt * 16;
    const int jlim = i0 + 32;
    const int jstart = c * CHUNK;
    if (jstart >= jlim) return;
    const int jend = min(jstart + CHUNK, jlim);
    const int nw = (jend - jstart + 31) >> 5;   // 32-j windows (<=8)

    __shared__ __align__(16) unsigned short p2s[2][8][16][40];  // 20 KB
    __shared__ __align__(16) float post_s[64];

    const int t = threadIdx.x;
    if (t < 64) post_s[t] = postp[t] * hsp[t & 7];

    const int lane = t & 63, w = t >> 6;
    const int iL = lane & 15, quad = lane >> 4;
    const int dW = w * 16 + iL;          // consumer d
    const int i_p = t & 15;              // producer i
    const int jj = t >> 4;               // producer j-group (0..15)
    const size_t ebase = (size_t)b * EPB + (size_t)(8 * tt * tt + 24 * tt) * 128;
    const unsigned short* __restrict__ ep = e16 + ebase + (size_t)i_p * 8;

    float linv[8];
#pragma unroll
    for (int h1 = 0; h1 < 8; ++h1)
        linv[h1] = 1.0f / lbuf[((size_t)(b * 128 + tt) * 8 + h1) * 16 + i_p];

    floatx4 y[8];
#pragma unroll
    for (int h2 = 0; h2 < 8; ++h2) y[h2] = (floatx4){0.f, 0.f, 0.f, 0.f};

    // 3-deep e prefetch: evA = current, evB = +1, evC = +2 (all static regs)
    ushortx8 evA[2], evB[2], evC[2];
    {
        const int j0c = jstart + jj * 2;
        int ja = min(j0c, jend - 1), jb2 = min(j0c + 1, jend - 1);
        evA[0] = *(const ushortx8*)(ep + (size_t)(ja * 16) * 8);
        evA[1] = *(const ushortx8*)(ep + (size_t)(jb2 * 16) * 8);
        ja = min(j0c + 32, jend - 1); jb2 = min(j0c + 33, jend - 1);
        evB[0] = *(const ushortx8*)(ep + (size_t)(ja * 16) * 8);
        evB[1] = *(const ushortx8*)(ep + (size_t)(jb2 * 16) * 8);
        ja = min(j0c + 64, jend - 1); jb2 = min(j0c + 65, jend - 1);
        evC[0] = *(const ushortx8*)(ep + (size_t)(ja * 16) * 8);
        evC[1] = *(const ushortx8*)(ep + (size_t)(jb2 * 16) * 8);
    }
    __syncthreads();   // post_s ready

    for (int n = 0; n < nw; ++n) {
        const int jw0 = jstart + n * 32;
        const int buf = n & 1;

        // V fragments issued first (L2 latency hides under postmix)
        int jbv = jw0 + quad * 8;
        if (jbv > J - 8) jbv = J - 8;    // only masked cols; p2s=0 for them
        short8 bF[8];
#pragma unroll
        for (int h2 = 0; h2 < 8; ++h2)
            bF[h2] = *(const short8*)(vt + ((size_t)(b * H + h2) * 64 + dW) * J + jbv);

        // e prefetch for window n+3 (clamped; harmless past the end)
        ushortx8 evT0, evT1;
        {
            const int wn = (n + 3 < nw) ? n + 3 : nw - 1;
            const int j0n = jstart + wn * 32 + jj * 2;
            const int ja = min(j0n, jend - 1), jb2 = min(j0n + 1, jend - 1);
            evT0 = *(const ushortx8*)(ep + (size_t)(ja * 16) * 8);
            evT1 = *(const ushortx8*)(ep + (size_t)(jb2 * 16) * 8);
        }

        // postmix current window from evA (packed f32)
        floatx2 p2v[2][4];
#pragma unroll
        for (int s = 0; s < 2; ++s) {
#pragma unroll
            for (int q = 0; q < 4; ++q) p2v[s][q] = (floatx2){0.f, 0.f};
            const int j = jw0 + jj * 2 + s;
            if (j < jend) {
#pragma unroll
                for (int h1 = 0; h1 < 8; ++h1) {
                    const float e = __uint_as_float(
                        (unsigned int)(unsigned short)evA[s][h1] << 16) * linv[h1];
                    const floatx2* po = (const floatx2*)(&post_s[h1 * 8]);
                    p2v[s][0] += e * po[0];
                    p2v[s][1] += e * po[1];
                    p2v[s][2] += e * po[2];
                    p2v[s][3] += e * po[3];
                }
            }
        }
#pragma unroll
        for (int h2 = 0; h2 < 8; ++h2)
            *(unsigned int*)(&p2s[buf][h2][i_p][jj * 2]) =
                pk2bf(p2v[0][h2 >> 1][h2 & 1], p2v[1][h2 >> 1][h2 & 1]);
        __syncthreads();   // single sync: dbuf protects cross-window reads

#pragma unroll
        for (int h2 = 0; h2 < 8; ++h2) {
            const short8 aF = *(const short8*)(&p2s[buf][h2][iL][quad * 8]);
            y[h2] = __builtin_amdgcn_mfma_f32_16x16x32_bf16(aF, bF[h2], y[h2], 0, 0, 0);
        }
        evA[0] = evB[0]; evA[1] = evB[1];
        evB[0] = evC[0]; evB[1] = evC[1];
        evC[0] = evT0;   evC[1] = evT1;
    }

#pragma unroll
    for (int h2 = 0; h2 < 8; ++h2) {
#pragma unroll
        for (int r = 0; r < 4; ++r) {
            const int ii = i0 + quad * 4 + r;
            atomicAdd(ao + ((size_t)b * N + ii) * DIM + h2 * 64 + dW, y[h2][r]);
        }
    }
}

// ---------------- K3: output projection GEMM — 128x128, B via gload_lds ---
__global__ __launch_bounds__(256)
void out_gemm(const float* __restrict__ ain, const unsigned short* __restrict__ WT,
              const float* __restrict__ bo, float* __restrict__ out)
{
    const int t = threadIdx.x;
    const int lane = t & 63, w = t >> 6;
    const int iL = lane & 15, quad = lane >> 4;
    const int wr = w >> 1, wc = w & 1;
    const int mb = blockIdx.x * 128;
    const int n0 = blockIdx.y * 128;

    __shared__ __align__(16) unsigned short As[2][128][32];  // 16 KB
    __shared__ __align__(16) unsigned short Bs[2][128][32];  // 16 KB

    const int ar = t >> 1, acb = (t & 1) * 16;            // A: 16 f32/thread
    const int srow = lane >> 2, scol = (lane & 3) * 8;    // B gload coords

    auto STAGEA = [&](int buf, int k0) {
        const float* src = ain + (size_t)(mb + ar) * DIM + k0 + acb;
        const float4 v0 = *(const float4*)(src);
        const float4 v1 = *(const float4*)(src + 4);
        const float4 v2 = *(const float4*)(src + 8);
        const float4 v3 = *(const float4*)(src + 12);
        ushortx8 o0 = { f2bf(v0.x), f2bf(v0.y), f2bf(v0.z), f2bf(v0.w),
                        f2bf(v1.x), f2bf(v1.y), f2bf(v1.z), f2bf(v1.w) };
        ushortx8 o1 = { f2bf(v2.x), f2bf(v2.y), f2bf(v2.z), f2bf(v2.w),
                        f2bf(v3.x), f2bf(v3.y), f2bf(v3.z), f2bf(v3.w) };
        *(ushortx8*)(&As[buf][ar][acb]) = o0;
        *(ushortx8*)(&As[buf][ar][acb + 8]) = o1;
    };
    auto STAGEB = [&](int buf, int k0) {
#pragma unroll
        for (int cc = 0; cc < 2; ++cc) {
            const int rb = w * 32 + cc * 16;
            const unsigned short* sb = WT + (size_t)(n0 + rb + srow) * DIM + k0 + scol;
            __builtin_amdgcn_global_load_lds(
                (const __attribute__((address_space(1))) unsigned int*)sb,
                (__attribute__((address_space(3))) unsigned int*)(&Bs[buf][rb][0]),
                16, 0, 0);
        }
    };

    floatx4 acc[4][4];
#pragma unroll
    for (int mi = 0; mi < 4; ++mi)
#pragma unroll
        for (int ni = 0; ni < 4; ++ni) acc[mi][ni] = (floatx4){0.f, 0.f, 0.f, 0.f};

    STAGEB(0, 0);
    STAGEA(0, 0);
    __syncthreads();

    for (int it = 0; it < 16; ++it) {
        const int buf = it & 1;
        if (it + 1 < 16) {
            STAGEB(buf ^ 1, (it + 1) * 32);
            STAGEA(buf ^ 1, (it + 1) * 32);
        }
        short8 aF[4], bF[4];
#pragma unroll
        for (int mi = 0; mi < 4; ++mi)
            aF[mi] = *(const short8*)(&As[buf][wr * 64 + mi * 16 + iL][quad * 8]);
#pragma unroll
        for (int ni = 0; ni < 4; ++ni)
            bF[ni] = *(const short8*)(&Bs[buf][wc * 64 + ni * 16 + iL][quad * 8]);
#pragma unroll
        for (int mi = 0; mi < 4; ++mi)
#pragma unroll
            for (int ni = 0; ni < 4; ++ni)
                acc[mi][ni] = __builtin_amdgcn_mfma_f32_16x16x32_bf16(
                    aF[mi], bF[ni], acc[mi][ni], 0, 0, 0);
        __syncthreads();
    }

#pragma unroll
    for (int mi = 0; mi < 4; ++mi) {
#pragma unroll
        for (int ni = 0; ni < 4; ++ni) {
            const int n = n0 + wc * 64 + ni * 16 + iL;
            const float bias = bo[n];
#pragma unroll
            for (int r = 0; r < 4; ++r) {
                const int m = mb + wr * 64 + mi * 16 + quad * 4 + r;
                out[(size_t)m * DIM + n] = acc[mi][ni][r] + bias;
            }
        }
    }
}

extern "C" void kernel_launch(void* const* d_in, const int* in_sizes, int n_in,
                              void* d_out, int out_size, void* d_ws, size_t ws_size,
                              hipStream_t stream)
{
    (void)in_sizes; (void)n_in; (void)out_size; (void)ws_size;
    const float* x      = (const float*)d_in[0];
    const float* Wq     = (const float*)d_in[1];
    const float* Wk     = (const float*)d_in[2];
    const float* Wv     = (const float*)d_in[3];
    const float* mem_k  = (const float*)d_in[4];
    const float* mem_v  = (const float*)d_in[5];
    const float* pre_p  = (const float*)d_in[6];
    const float* post_p = (const float*)d_in[7];
    const float* hs     = (const float*)d_in[8];
    const float* Wo     = (const float*)d_in[9];
    const float* bo     = (const float*)d_in[10];
    float* out = (float*)d_out;

    constexpr size_t NAO  = (size_t)B * N * DIM;        // 2,097,152 f32
    constexpr size_t NLB  = (size_t)B * 128 * H * 16;   //    32,768 f32
    constexpr size_t NW   = (size_t)DIM * DIM;          //   262,144 u16 each
    constexpr size_t NQ   = (size_t)B * H * N * 64;     // 2,097,152 u16
    constexpr size_t NK   = (size_t)B * H * J * 64;     // 2,113,536 u16
    constexpr size_t NX   = (size_t)B * N * DIM;        // 2,097,152 u16

    float* ws = (float*)d_ws;
    float* ao   = ws;
    float* lbuf = ao + NAO;
    unsigned short* wtq  = (unsigned short*)(lbuf + NLB);
    unsigned short* wtk  = wtq + NW;
    unsigned short* wtv  = wtk + NW;
    unsigned short* wto  = wtv + NW;
    unsigned short* q16  = wto + NW;
    unsigned short* k16  = q16 + NQ;
    unsigned short* v16  = k16 + NK;
    unsigned short* x16  = v16 + NK;
    unsigned short* e16  = x16 + NX;

    // fused prologue: x conv (1024) + W^T (256) + memkv (32) + zero (2080)
    prep<<<dim3(3392), 256, 0, stream>>>(x, Wq, Wk, Wv, Wo, mem_k, mem_v,
                                         x16, wtq, wtk, wtv, wto, k16, v16, ao);
    qkv_gemm<<<dim3(32, 4, 3), 256, 0, stream>>>(x16, wtq, wtk, wtv, q16, k16, v16);
    attn_scores<<<dim3(CMAX, 128, B), 256, 0, stream>>>(q16, k16, pre_p, lbuf, e16);
    attn_pv2<<<dim3(CMAX, 128, B), 256, 0, stream>>>(e16, v16, post_p, hs, lbuf, ao);
    out_gemm<<<dim3(32, 4), 256, 0, stream>>>(ao, wto, bo, out);
}

// Round 13
// 221.471 us; speedup vs baseline: 1.0705x; 1.0705x over previous
//
#include <hip/hip_runtime.h>
#include <math.h>

namespace {
constexpr int B = 2;
constexpr int N = 2048;
constexpr int DIM = 512;
constexpr int H = 8;
constexpr int MEM = 16;
constexpr int J = MEM + N;       // 2064
constexpr int CHUNK = 256;
constexpr int CMAX = 9;          // ceil(2064/256)
constexpr float S2 = 0.125f * 1.4426950408889634f;  // SCALE * log2(e)
// e-buffer: per b, sum_t (16t+32) j-rows * 16 i * 8 h1 bf16 elems
constexpr size_t EPB = 17170432;        // 134144 * 128
}

typedef __attribute__((ext_vector_type(8))) short short8;
typedef __attribute__((ext_vector_type(2))) float floatx2;
typedef __attribute__((ext_vector_type(4))) float floatx4;
typedef __attribute__((ext_vector_type(4))) unsigned short ushortx4;
typedef __attribute__((ext_vector_type(8))) unsigned short ushortx8;

__device__ inline unsigned short f2bf(float f) {
    unsigned int u = __float_as_uint(f);
    u += 0x7fffu + ((u >> 16) & 1u);   // RNE
    return (unsigned short)(u >> 16);
}
__device__ inline unsigned int pk2bf(float a, float b) {
    return ((__float_as_uint(a) + 0x8000u) >> 16) |
           ((__float_as_uint(b) + 0x8000u) & 0xffff0000u);
}

// ---------------- P: fused prologue — x conv, W transposes, memkv, zeroing
// block ranges:  [0,1024)   x fp32->bf16   (1024 blocks)
//                [1024,1280) W^T bf16      (4 matrices x 64 blocks)
//                [1280,1312) mem_k/mem_v   (32 blocks)
//                [1312,3392) zero ao+lbuf  (2080 blocks x 1024 f32)
__global__ __launch_bounds__(256)
void prep(const float* __restrict__ x,
          const float* __restrict__ Wq, const float* __restrict__ Wk,
          const float* __restrict__ Wv, const float* __restrict__ Wo,
          const float* __restrict__ mem_k, const float* __restrict__ mem_v,
          unsigned short* __restrict__ x16,
          unsigned short* __restrict__ tq, unsigned short* __restrict__ tk,
          unsigned short* __restrict__ tv, unsigned short* __restrict__ to_,
          unsigned short* __restrict__ k16, unsigned short* __restrict__ vt16,
          float* __restrict__ zbuf)
{
    __shared__ __align__(16) unsigned short tile[64][72];
    const int bid = blockIdx.x;
    const int t = threadIdx.x;

    if (bid < 1024) {                      // ---- x conversion
        const size_t base = ((size_t)bid * 256 + t) * 8;
        const float4 a = *(const float4*)(x + base);
        const float4 b = *(const float4*)(x + base + 4);
        ushortx8 o = { f2bf(a.x), f2bf(a.y), f2bf(a.z), f2bf(a.w),
                       f2bf(b.x), f2bf(b.y), f2bf(b.z), f2bf(b.w) };
        *(ushortx8*)(x16 + base) = o;
        return;
    }
    if (bid < 1280) {                      // ---- W -> WT bf16 transpose
        const int idx = bid - 1024;
        const int z = idx >> 6, rem = idx & 63;
        const float* __restrict__ W = (z == 0) ? Wq : (z == 1) ? Wk : (z == 2) ? Wv : Wo;
        unsigned short* __restrict__ WT = (z == 0) ? tq : (z == 1) ? tk : (z == 2) ? tv : to_;
        const int k0 = (rem >> 3) * 64, n0 = (rem & 7) * 64;

        const int rrow = t >> 4, rcol = (t & 15) * 4;
#pragma unroll
        for (int rr = 0; rr < 4; ++rr) {
            const int row = rrow + rr * 16;
            const float4 v = *(const float4*)(W + (size_t)(k0 + row) * DIM + n0 + rcol);
            tile[rcol + 0][row] = f2bf(v.x);
            tile[rcol + 1][row] = f2bf(v.y);
            tile[rcol + 2][row] = f2bf(v.z);
            tile[rcol + 3][row] = f2bf(v.w);
        }
        __syncthreads();
        const int orow = t >> 2, oseg = (t & 3) * 16;
        *(ushortx8*)(WT + (size_t)(n0 + orow) * DIM + k0 + oseg) =
            *(const ushortx8*)(&tile[orow][oseg]);
        *(ushortx8*)(WT + (size_t)(n0 + orow) * DIM + k0 + oseg + 8) =
            *(const ushortx8*)(&tile[orow][oseg + 8]);
        return;
    }
    if (bid < 1312) {                      // ---- mem_k/mem_v scatter
        const int idx = (bid - 1280) * 256 + t;  // H*MEM*64 = 8192
        if (idx >= H * MEM * 64) return;
        const int h0 = idx >> 10;
        const int rd = idx & 1023;
        const int r = rd >> 6, d = rd & 63;
        const unsigned short kk = f2bf(mem_k[idx]);
        const unsigned short vv = f2bf(mem_v[idx]);
#pragma unroll
        for (int bb = 0; bb < B; ++bb) {
            k16[((size_t)(bb * H + h0) * J + r) * 64 + d] = kk;
            vt16[((size_t)(bb * H + h0) * 64 + d) * J + r] = vv;
        }
        return;
    }
    {                                      // ---- zero ao + lbuf (8.52 MB)
        const size_t off = ((size_t)(bid - 1312) * 256 + t) * 4;
        *(float4*)(zbuf + off) = make_float4(0.f, 0.f, 0.f, 0.f);
    }
}

// ---------------- K1: QKV projection GEMM (bf16 in, LDS dbuf, bf16 MFMA) --
// Output layouts: q16[b,h,N,64] / k16[b,h,J,64] / vt16[b,h,64,J]
__global__ __launch_bounds__(256)
void qkv_gemm(const unsigned short* __restrict__ x16, const unsigned short* __restrict__ tq,
              const unsigned short* __restrict__ tk, const unsigned short* __restrict__ tv,
              unsigned short* __restrict__ q16, unsigned short* __restrict__ k16,
              unsigned short* __restrict__ vt16)
{
    const int which = blockIdx.z;
    const unsigned short* __restrict__ WT = (which == 0) ? tq : (which == 1) ? tk : tv;
    const int t = threadIdx.x;
    const int lane = t & 63, w = t >> 6;
    const int iL = lane & 15, quad = lane >> 4;
    const int mb = blockIdx.x * 64;
    const int n0 = blockIdx.y * 64;

    __shared__ __align__(16) unsigned short As[2][64][32];  // 8 KB
    __shared__ __align__(16) unsigned short Bs[2][64][32];  // 8 KB

    const int r0 = t >> 2, s8 = (t & 3) * 8;

    floatx4 acc[4];
#pragma unroll
    for (int ng = 0; ng < 4; ++ng) acc[ng] = (floatx4){0.f, 0.f, 0.f, 0.f};

    {
        *(ushortx8*)(&As[0][r0][s8]) =
            *(const ushortx8*)(x16 + (size_t)(mb + r0) * DIM + s8);
        *(ushortx8*)(&Bs[0][r0][s8]) =
            *(const ushortx8*)(WT + (size_t)(n0 + r0) * DIM + s8);
    }
    __syncthreads();

#pragma unroll
    for (int it = 0; it < 16; ++it) {
        const int buf = it & 1;
        if (it + 1 < 16) {
            const int k0 = (it + 1) * 32;
            const ushortx8 av = *(const ushortx8*)(x16 + (size_t)(mb + r0) * DIM + k0 + s8);
            const ushortx8 bv = *(const ushortx8*)(WT + (size_t)(n0 + r0) * DIM + k0 + s8);
            *(ushortx8*)(&As[buf ^ 1][r0][s8]) = av;
            *(ushortx8*)(&Bs[buf ^ 1][r0][s8]) = bv;
        }
        const short8 af = *(const short8*)(&As[buf][w * 16 + iL][quad * 8]);
#pragma unroll
        for (int ng = 0; ng < 4; ++ng) {
            const short8 bf = *(const short8*)(&Bs[buf][ng * 16 + iL][quad * 8]);
            acc[ng] = __builtin_amdgcn_mfma_f32_16x16x32_bf16(af, bf, acc[ng], 0, 0, 0);
        }
        __syncthreads();
    }

    const int mbw = mb + w * 16;
    const int h0 = n0 >> 6;
    if (which == 2) {
#pragma unroll
        for (int ng = 0; ng < 4; ++ng) {
            const int d = ng * 16 + iL;
#pragma unroll
            for (int r = 0; r < 4; ++r) {
                const int m = mbw + quad * 4 + r;
                const int bb = m >> 11, ii = m & (N - 1);
                vt16[((size_t)(bb * H + h0) * 64 + d) * J + MEM + ii] = f2bf(acc[ng][r]);
            }
        }
    } else {
        unsigned short* dst = (which == 0) ? q16 : k16;
#pragma unroll
        for (int ng = 0; ng < 4; ++ng) {
            const int d = ng * 16 + iL;
#pragma unroll
            for (int r = 0; r < 4; ++r) {
                const int m = mbw + quad * 4 + r;
                const int bb = m >> 11, ii = m & (N - 1);
                const size_t rowbase = (which == 0)
                    ? ((size_t)(bb * H + h0) * N + ii)
                    : ((size_t)(bb * H + h0) * J + MEM + ii);
                dst[rowbase * 64 + d] = f2bf(acc[ng][r]);
            }
        }
    }
}

// ---------------- K2a: scores pass — r8-exact (measured 64.9 us) ----------
// QK + premix + exp; store e; sum l. q-tile in LDS; k prefetch 1 h0 ahead.
__global__ __launch_bounds__(256)
void attn_scores(const unsigned short* __restrict__ qb, const unsigned short* __restrict__ kb,
                 const float* __restrict__ prep_p, float* __restrict__ lbuf,
                 unsigned short* __restrict__ e16)
{
    const int c = blockIdx.x, tt = 127 - blockIdx.y, b = blockIdx.z;
    const int i0 = tt * 16;
    const int jlim = i0 + 32;            // == min(J, i0+32) for all tt
    const int jstart = c * CHUNK;
    if (jstart >= jlim) return;
    const int jend = min(jstart + CHUNK, jlim);

    __shared__ __align__(16) unsigned short q_s[8][16][64];  // 16 KB
    __shared__ __align__(16) float pre_s[64];
    const int t = threadIdx.x;
    if (t < 64) pre_s[t] = prep_p[t];
#pragma unroll
    for (int u4 = 0; u4 < 4; ++u4) {
        const int u = t + u4 * 256;          // over 1024 groups of 8
        const int h = u >> 7, rem = u & 127, i = rem >> 3, seg = (rem & 7) * 8;
        *(ushortx8*)(&q_s[h][i][seg]) =
            *(const ushortx8*)(qb + ((size_t)(b * H + h) * N + i0 + i) * 64 + seg);
    }
    __syncthreads();

    const int lane = t & 63, w = t >> 6;
    const int iL = lane & 15, quad = lane >> 4;
    const int i = i0 + iL;
    const size_t ebase = (size_t)b * EPB + (size_t)(8 * tt * tt + 24 * tt) * 128;

    float l_acc[8];
#pragma unroll
    for (int h1 = 0; h1 < 8; ++h1) l_acc[h1] = 0.f;

    bool any = false;
    for (int j0 = jstart + w * 16; j0 < jend; j0 += 64) {
        any = true;
        float dots[8][4];
#pragma unroll
        for (int h1 = 0; h1 < 8; ++h1)
#pragma unroll
            for (int r = 0; r < 4; ++r) dots[h1][r] = 0.f;

        // k prefetch chain over h0
        const unsigned short* kp0 = kb + ((size_t)(b * H) * J + j0 + iL) * 64 + quad * 8;
        short8 kc0 = *(const short8*)kp0;
        short8 kc1 = *(const short8*)(kp0 + 32);
#pragma unroll
        for (int h0 = 0; h0 < 8; ++h0) {
            short8 kn0, kn1;
            if (h0 < 7) {
                const unsigned short* kpn =
                    kb + ((size_t)(b * H + h0 + 1) * J + j0 + iL) * 64 + quad * 8;
                kn0 = *(const short8*)kpn;
                kn1 = *(const short8*)(kpn + 32);
            }
            const short8 qf0 = *(const short8*)(&q_s[h0][iL][quad * 8]);
            const short8 qf1 = *(const short8*)(&q_s[h0][iL][quad * 8 + 32]);
            floatx4 a = {0.f, 0.f, 0.f, 0.f};
            a = __builtin_amdgcn_mfma_f32_16x16x32_bf16(kc0, qf0, a, 0, 0, 0);
            a = __builtin_amdgcn_mfma_f32_16x16x32_bf16(kc1, qf1, a, 0, 0, 0);
            const float4 pr0 = *(const float4*)(&pre_s[h0 * 8]);
            const float4 pr1 = *(const float4*)(&pre_s[h0 * 8 + 4]);
#pragma unroll
            for (int r = 0; r < 4; ++r) {
                const float av = a[r];
                dots[0][r] = fmaf(av, pr0.x, dots[0][r]);
                dots[1][r] = fmaf(av, pr0.y, dots[1][r]);
                dots[2][r] = fmaf(av, pr0.z, dots[2][r]);
                dots[3][r] = fmaf(av, pr0.w, dots[3][r]);
                dots[4][r] = fmaf(av, pr1.x, dots[4][r]);
                dots[5][r] = fmaf(av, pr1.y, dots[5][r]);
                dots[6][r] = fmaf(av, pr1.z, dots[6][r]);
                dots[7][r] = fmaf(av, pr1.w, dots[7][r]);
            }
            kc0 = kn0; kc1 = kn1;
        }

        unsigned int epk[4][4];
        float etmp[4];
#pragma unroll
        for (int h1 = 0; h1 < 8; ++h1) {
            const float slopeE = 1.4426950408889634f / (float)(2 << h1);
#pragma unroll
            for (int r = 0; r < 4; ++r) {
                const int j = j0 + quad * 4 + r;
                const bool vis = (j - MEM) <= i;
                const float e = vis ? exp2f(fmaf(dots[h1][r], S2, slopeE * (float)(j - i - MEM)))
                                    : 0.f;
                l_acc[h1] += e;
                if (h1 & 1) epk[r][h1 >> 1] = pk2bf(etmp[r], e);
                else        etmp[r] = e;
            }
        }
#pragma unroll
        for (int r = 0; r < 4; ++r) {
            uint4 o = make_uint4(epk[r][0], epk[r][1], epk[r][2], epk[r][3]);
            *(uint4*)(e16 + ebase + (size_t)((j0 + quad * 4 + r) * 16 + iL) * 8) = o;
        }
    }

#pragma unroll
    for (int h1 = 0; h1 < 8; ++h1) {
        float v = l_acc[h1];
        v += __shfl_xor(v, 16);
        v += __shfl_xor(v, 32);
        if (quad == 0 && any)
            atomicAdd(lbuf + ((size_t)(b * 128 + tt) * 8 + h1) * 16 + iL, v);
    }
}

// ---------------- K2b: pv pass — 3-deep e-prefetch, dbuf LDS, PV-MFMA -----
__global__ __launch_bounds__(256)
void attn_pv2(const unsigned short* __restrict__ e16, const unsigned short* __restrict__ vt,
              const float* __restrict__ postp, const float* __restrict__ hsp,
              const float* __restrict__ lbuf, float* __restrict__ ao)
{
    const int c = blockIdx.x, tt = 127 - blockIdx.y, b = blockIdx.z;
    const int i0 = tt * 16;
    const int jlim = i0 + 32;
    const int jstart = c * CHUNK;
    if (jstart >= jlim) return;
    const int jend = min(jstart + CHUNK, jlim);
    const int nw = (jend - jstart + 31) >> 5;   // 32-j windows (<=8)

    __shared__ __align__(16) unsigned short p2s[2][8][16][40];  // 20 KB
    __shared__ __align__(16) float post_s[64];

    const int t = threadIdx.x;
    if (t < 64) post_s[t] = postp[t] * hsp[t & 7];

    const int lane = t & 63, w = t >> 6;
    const int iL = lane & 15, quad = lane >> 4;
    const int dW = w * 16 + iL;          // consumer d
    const int i_p = t & 15;              // producer i
    const int jj = t >> 4;               // producer j-group (0..15)
    const size_t ebase = (size_t)b * EPB + (size_t)(8 * tt * tt + 24 * tt) * 128;
    const unsigned short* __restrict__ ep = e16 + ebase + (size_t)i_p * 8;

    float linv[8];
#pragma unroll
    for (int h1 = 0; h1 < 8; ++h1)
        linv[h1] = 1.0f / lbuf[((size_t)(b * 128 + tt) * 8 + h1) * 16 + i_p];

    floatx4 y[8];
#pragma unroll
    for (int h2 = 0; h2 < 8; ++h2) y[h2] = (floatx4){0.f, 0.f, 0.f, 0.f};

    // 3-deep e prefetch: evA = current, evB = +1, evC = +2 (all static regs)
    ushortx8 evA[2], evB[2], evC[2];
    {
        const int j0c = jstart + jj * 2;
        int ja = min(j0c, jend - 1), jb2 = min(j0c + 1, jend - 1);
        evA[0] = *(const ushortx8*)(ep + (size_t)(ja * 16) * 8);
        evA[1] = *(const ushortx8*)(ep + (size_t)(jb2 * 16) * 8);
        ja = min(j0c + 32, jend - 1); jb2 = min(j0c + 33, jend - 1);
        evB[0] = *(const ushortx8*)(ep + (size_t)(ja * 16) * 8);
        evB[1] = *(const ushortx8*)(ep + (size_t)(jb2 * 16) * 8);
        ja = min(j0c + 64, jend - 1); jb2 = min(j0c + 65, jend - 1);
        evC[0] = *(const ushortx8*)(ep + (size_t)(ja * 16) * 8);
        evC[1] = *(const ushortx8*)(ep + (size_t)(jb2 * 16) * 8);
    }
    __syncthreads();   // post_s ready

    for (int n = 0; n < nw; ++n) {
        const int jw0 = jstart + n * 32;
        const int buf = n & 1;

        // V fragments issued first (L2 latency hides under postmix)
        int jbv = jw0 + quad * 8;
        if (jbv > J - 8) jbv = J - 8;    // only masked cols; p2s=0 for them
        short8 bF[8];
#pragma unroll
        for (int h2 = 0; h2 < 8; ++h2)
            bF[h2] = *(const short8*)(vt + ((size_t)(b * H + h2) * 64 + dW) * J + jbv);

        // e prefetch for window n+3 (clamped; harmless past the end)
        ushortx8 evT0, evT1;
        {
            const int wn = (n + 3 < nw) ? n + 3 : nw - 1;
            const int j0n = jstart + wn * 32 + jj * 2;
            const int ja = min(j0n, jend - 1), jb2 = min(j0n + 1, jend - 1);
            evT0 = *(const ushortx8*)(ep + (size_t)(ja * 16) * 8);
            evT1 = *(const ushortx8*)(ep + (size_t)(jb2 * 16) * 8);
        }

        // postmix current window from evA (packed f32)
        floatx2 p2v[2][4];
#pragma unroll
        for (int s = 0; s < 2; ++s) {
#pragma unroll
            for (int q = 0; q < 4; ++q) p2v[s][q] = (floatx2){0.f, 0.f};
            const int j = jw0 + jj * 2 + s;
            if (j < jend) {
#pragma unroll
                for (int h1 = 0; h1 < 8; ++h1) {
                    const float e = __uint_as_float(
                        (unsigned int)(unsigned short)evA[s][h1] << 16) * linv[h1];
                    const floatx2* po = (const floatx2*)(&post_s[h1 * 8]);
                    p2v[s][0] += e * po[0];
                    p2v[s][1] += e * po[1];
                    p2v[s][2] += e * po[2];
                    p2v[s][3] += e * po[3];
                }
            }
        }
#pragma unroll
        for (int h2 = 0; h2 < 8; ++h2)
            *(unsigned int*)(&p2s[buf][h2][i_p][jj * 2]) =
                pk2bf(p2v[0][h2 >> 1][h2 & 1], p2v[1][h2 >> 1][h2 & 1]);
        __syncthreads();   // single sync: dbuf protects cross-window reads

#pragma unroll
        for (int h2 = 0; h2 < 8; ++h2) {
            const short8 aF = *(const short8*)(&p2s[buf][h2][iL][quad * 8]);
            y[h2] = __builtin_amdgcn_mfma_f32_16x16x32_bf16(aF, bF[h2], y[h2], 0, 0, 0);
        }
        evA[0] = evB[0]; evA[1] = evB[1];
        evB[0] = evC[0]; evB[1] = evC[1];
        evC[0] = evT0;   evC[1] = evT1;
    }

#pragma unroll
    for (int h2 = 0; h2 < 8; ++h2) {
#pragma unroll
        for (int r = 0; r < 4; ++r) {
            const int ii = i0 + quad * 4 + r;
            atomicAdd(ao + ((size_t)b * N + ii) * DIM + h2 * 64 + dW, y[h2][r]);
        }
    }
}

// ---------------- K3: output projection GEMM + bias (LDS dbuf, bf16 MFMA) -
__global__ __launch_bounds__(256)
void out_gemm(const float* __restrict__ ain, const unsigned short* __restrict__ WT,
              const float* __restrict__ bo, float* __restrict__ out)
{
    const int t = threadIdx.x;
    const int lane = t & 63, w = t >> 6;
    const int iL = lane & 15, quad = lane >> 4;
    const int mb = blockIdx.x * 64;
    const int n0 = blockIdx.y * 64;

    __shared__ __align__(16) unsigned short As[2][64][32];
    __shared__ __align__(16) unsigned short Bs[2][64][32];

    const int ar0 = t >> 3, as4 = (t & 7) * 4;
    const int br0 = t >> 2, bs8 = (t & 3) * 8;

    floatx4 acc[4];
#pragma unroll
    for (int ng = 0; ng < 4; ++ng) acc[ng] = (floatx4){0.f, 0.f, 0.f, 0.f};

    {
        const float4 v0 = *(const float4*)(ain + (size_t)(mb + ar0) * DIM + as4);
        const float4 v1 = *(const float4*)(ain + (size_t)(mb + ar0 + 32) * DIM + as4);
        ushortx4 o0 = { f2bf(v0.x), f2bf(v0.y), f2bf(v0.z), f2bf(v0.w) };
        ushortx4 o1 = { f2bf(v1.x), f2bf(v1.y), f2bf(v1.z), f2bf(v1.w) };
        *(ushortx4*)(&As[0][ar0][as4]) = o0;
        *(ushortx4*)(&As[0][ar0 + 32][as4]) = o1;
        *(ushortx8*)(&Bs[0][br0][bs8]) =
            *(const ushortx8*)(WT + (size_t)(n0 + br0) * DIM + bs8);
    }
    __syncthreads();

#pragma unroll
    for (int it = 0; it < 16; ++it) {
        const int buf = it & 1;
        if (it + 1 < 16) {
            const int k0 = (it + 1) * 32;
            const float4 v0 = *(const float4*)(ain + (size_t)(mb + ar0) * DIM + k0 + as4);
            const float4 v1 = *(const float4*)(ain + (size_t)(mb + ar0 + 32) * DIM + k0 + as4);
            const ushortx8 bv =
                *(const ushortx8*)(WT + (size_t)(n0 + br0) * DIM + k0 + bs8);
            ushortx4 o0 = { f2bf(v0.x), f2bf(v0.y), f2bf(v0.z), f2bf(v0.w) };
            ushortx4 o1 = { f2bf(v1.x), f2bf(v1.y), f2bf(v1.z), f2bf(v1.w) };
            *(ushortx4*)(&As[buf ^ 1][ar0][as4]) = o0;
            *(ushortx4*)(&As[buf ^ 1][ar0 + 32][as4]) = o1;
            *(ushortx8*)(&Bs[buf ^ 1][br0][bs8]) = bv;
        }
        const short8 af = *(const short8*)(&As[buf][w * 16 + iL][quad * 8]);
#pragma unroll
        for (int ng = 0; ng < 4; ++ng) {
            const short8 bf = *(const short8*)(&Bs[buf][ng * 16 + iL][quad * 8]);
            acc[ng] = __builtin_amdgcn_mfma_f32_16x16x32_bf16(af, bf, acc[ng], 0, 0, 0);
        }
        __syncthreads();
    }

    const int mbw = mb + w * 16;
#pragma unroll
    for (int ng = 0; ng < 4; ++ng) {
        const int n = n0 + ng * 16 + iL;
        const float bias = bo[n];
#pragma unroll
        for (int r = 0; r < 4; ++r) {
            const int m = mbw + quad * 4 + r;
            out[(size_t)m * DIM + n] = acc[ng][r] + bias;
        }
    }
}

extern "C" void kernel_launch(void* const* d_in, const int* in_sizes, int n_in,
                              void* d_out, int out_size, void* d_ws, size_t ws_size,
                              hipStream_t stream)
{
    (void)in_sizes; (void)n_in; (void)out_size; (void)ws_size;
    const float* x      = (const float*)d_in[0];
    const float* Wq     = (const float*)d_in[1];
    const float* Wk     = (const float*)d_in[2];
    const float* Wv     = (const float*)d_in[3];
    const float* mem_k  = (const float*)d_in[4];
    const float* mem_v  = (const float*)d_in[5];
    const float* pre_p  = (const float*)d_in[6];
    const float* post_p = (const float*)d_in[7];
    const float* hs     = (const float*)d_in[8];
    const float* Wo     = (const float*)d_in[9];
    const float* bo     = (const float*)d_in[10];
    float* out = (float*)d_out;

    constexpr size_t NAO  = (size_t)B * N * DIM;        // 2,097,152 f32
    constexpr size_t NLB  = (size_t)B * 128 * H * 16;   //    32,768 f32
    constexpr size_t NW   = (size_t)DIM * DIM;          //   262,144 u16 each
    constexpr size_t NQ   = (size_t)B * H * N * 64;     // 2,097,152 u16
    constexpr size_t NK   = (size_t)B * H * J * 64;     // 2,113,536 u16
    constexpr size_t NX   = (size_t)B * N * DIM;        // 2,097,152 u16

    float* ws = (float*)d_ws;
    float* ao   = ws;
    float* lbuf = ao + NAO;
    unsigned short* wtq  = (unsigned short*)(lbuf + NLB);
    unsigned short* wtk  = wtq + NW;
    unsigned short* wtv  = wtk + NW;
    unsigned short* wto  = wtv + NW;
    unsigned short* q16  = wto + NW;
    unsigned short* k16  = q16 + NQ;
    unsigned short* v16  = k16 + NK;
    unsigned short* x16  = v16 + NK;
    unsigned short* e16  = x16 + NX;

    // fused prologue: x conv (1024) + W^T (256) + memkv (32) + zero (2080)
    prep<<<dim3(3392), 256, 0, stream>>>(x, Wq, Wk, Wv, Wo, mem_k, mem_v,
                                         x16, wtq, wtk, wtv, wto, k16, v16, ao);
    qkv_gemm<<<dim3(64, 8, 3), 256, 0, stream>>>(x16, wtq, wtk, wtv, q16, k16, v16);
    attn_scores<<<dim3(CMAX, 128, B), 256, 0, stream>>>(q16, k16, pre_p, lbuf, e16);
    attn_pv2<<<dim3(CMAX, 128, B), 256, 0, stream>>>(e16, v16, post_p, hs, lbuf, ao);
    out_gemm<<<dim3(64, 8), 256, 0, stream>>>(ao, wto, bo, out);
}